// Round 6
// baseline (261.857 us; speedup 1.0000x reference)
//
#include <hip/hip_runtime.h>
#include <stdint.h>

typedef unsigned short u16;
typedef __attribute__((ext_vector_type(8))) short short8;
typedef __attribute__((ext_vector_type(4))) short short4v;
typedef __attribute__((ext_vector_type(4))) float f32x4;

#define MFMA16 __builtin_amdgcn_mfma_f32_16x16x32_bf16

#define GLOAD_LDS16(gsrc, ldst) \
  __builtin_amdgcn_global_load_lds((const __attribute__((address_space(1))) void*)(gsrc), \
                                   (__attribute__((address_space(3))) void*)(ldst), 16, 0, 0)

__device__ __forceinline__ u16 f2bf(float x) {
  union { float f; uint32_t u; } v; v.f = x;
  uint32_t r = v.u + 0x7FFFu + ((v.u >> 16) & 1u);
  return (u16)(r >> 16);
}
__device__ __forceinline__ float bf2f(u16 b) {
  union { uint32_t u; float f; } v; v.u = ((uint32_t)b) << 16;
  return v.f;
}

// ---------------- convert f32 -> bf16 (elementwise, vectorized) ----------------
__global__ __launch_bounds__(256) void convert_bf16_kernel(
    const float* __restrict__ in, u16* __restrict__ out, int n) {
  int i = (blockIdx.x * 256 + threadIdx.x) * 8;
  if (i >= n) return;
  float4 a = *(const float4*)(in + i);
  float4 b = *(const float4*)(in + i + 4);
  short8 t;
  t[0] = (short)f2bf(a.x); t[1] = (short)f2bf(a.y);
  t[2] = (short)f2bf(a.z); t[3] = (short)f2bf(a.w);
  t[4] = (short)f2bf(b.x); t[5] = (short)f2bf(b.y);
  t[6] = (short)f2bf(b.z); t[7] = (short)f2bf(b.w);
  *(short8*)(out + i) = t;
}

// ---------------- transpose f32 [K][N] -> bf16 [N][K] (64x64 tiles) ----------------
__global__ __launch_bounds__(256) void transpose_w64(
    const float* __restrict__ W, u16* __restrict__ WT, int KK, int NN) {
  __shared__ float tile[64][68];
  const int t = threadIdx.x;
  const int k0 = blockIdx.x * 64, n0 = blockIdx.y * 64;
  {
    int r = t >> 2, c0 = (t & 3) * 16;
    const float* src = W + (size_t)(k0 + r) * NN + n0 + c0;
#pragma unroll
    for (int j = 0; j < 16; j += 4) {
      float4 v = *(const float4*)(src + j);
      tile[r][c0 + j + 0] = v.x; tile[r][c0 + j + 1] = v.y;
      tile[r][c0 + j + 2] = v.z; tile[r][c0 + j + 3] = v.w;
    }
  }
  __syncthreads();
  {
    int n = t >> 2, kq = (t & 3) * 16;
    short8 t0, t1;
#pragma unroll
    for (int j = 0; j < 8; ++j)  t0[j] = (short)f2bf(tile[kq + j][n]);
#pragma unroll
    for (int j = 0; j < 8; ++j)  t1[j] = (short)f2bf(tile[kq + 8 + j][n]);
    u16* dst = WT + (size_t)(n0 + n) * KK + k0 + kq;
    *(short8*)dst = t0;
    *(short8*)(dst + 8) = t1;
  }
}

// ---------------- transpose V bf16 [b*2048+s][h*64+c] -> VT [(b*16+h)*64+c][s] ----------------
__global__ __launch_bounds__(256) void transpose_v64(
    const u16* __restrict__ vin, u16* __restrict__ vout) {
  __shared__ u16 tile[64][80];
  const int t = threadIdx.x;
  const int s0 = blockIdx.x * 64;
  const int bh = blockIdx.y;  // b*16+h
  const int b = bh >> 4, h = bh & 15;
  {
    int r = t >> 2, c0 = (t & 3) * 16;
    const u16* src = vin + (size_t)(b * 2048 + s0 + r) * 1024 + h * 64 + c0;
    *(short8*)&tile[r][c0] = *(const short8*)src;
    *(short8*)&tile[r][c0 + 8] = *(const short8*)(src + 8);
  }
  __syncthreads();
  {
    int c = t >> 2, s4 = (t & 3) * 16;
    short8 t0, t1;
#pragma unroll
    for (int j = 0; j < 8; ++j) t0[j] = (short)tile[s4 + j][c];
#pragma unroll
    for (int j = 0; j < 8; ++j) t1[j] = (short)tile[s4 + 8 + j][c];
    u16* dst = vout + (size_t)(bh * 64 + c) * 2048 + s0 + s4;
    *(short8*)dst = t0;
    *(short8*)(dst + 8) = t1;
  }
}

// ---------------- GEMM: D[r][n] = sum_k A[r][k]*BT[n][k], m97-style 128x128/BK=64 ----------------
__global__ __launch_bounds__(256) void gemm_bt128(
    const u16* __restrict__ A, const u16* __restrict__ BTbase,
    void* __restrict__ dstbase, const float* __restrict__ bvec, int mode) {
  const int K = 1024;
  const int tid = threadIdx.x, lane = tid & 63, w = tid >> 6;
  const int wr = w >> 1, wc = w & 1;
  const int l15 = lane & 15, lg = lane >> 4;
  const int z = (mode < 0) ? (int)blockIdx.z : mode;
  const u16* BT = (mode < 0) ? BTbase + (size_t)z * 1024 * 1024 : BTbase;
  const int rbase = blockIdx.x * 128;
  const int nbase = blockIdx.y * 128;
  __shared__ u16 lsA[128 * 64];
  __shared__ u16 lsB[128 * 64];
  f32x4 acc[4][4] = {};
  const int col8 = (lane & 7) * 8;
  for (int kt = 0; kt < K / 64; ++kt) {
#pragma unroll
    for (int i = 0; i < 4; ++i) {
      int row = w * 32 + i * 8 + (lane >> 3);
      const u16* sa = A + (size_t)(rbase + row) * K + kt * 64 + col8;
      GLOAD_LDS16(sa, lsA + (w * 32 + i * 8) * 64 + lane * 8);
      const u16* sb = BT + (size_t)(nbase + row) * K + kt * 64 + col8;
      GLOAD_LDS16(sb, lsB + (w * 32 + i * 8) * 64 + lane * 8);
    }
    __syncthreads();
#pragma unroll
    for (int kk = 0; kk < 2; ++kk) {
      short8 af[4], bfr[4];
#pragma unroll
      for (int m = 0; m < 4; ++m)
        af[m] = *(const short8*)&lsA[(wr * 64 + m * 16 + l15) * 64 + kk * 32 + lg * 8];
#pragma unroll
      for (int n = 0; n < 4; ++n)
        bfr[n] = *(const short8*)&lsB[(wc * 64 + n * 16 + l15) * 64 + kk * 32 + lg * 8];
#pragma unroll
      for (int m = 0; m < 4; ++m)
#pragma unroll
        for (int n = 0; n < 4; ++n)
          acc[m][n] = MFMA16(af[m], bfr[n], acc[m][n], 0, 0, 0);
    }
    __syncthreads();
  }
  const int r0 = rbase + wr * 64;
  const int c0 = nbase + wc * 64;
  if (z == 4) {
    float* out = (float*)dstbase;
#pragma unroll
    for (int m = 0; m < 4; ++m)
#pragma unroll
      for (int n = 0; n < 4; ++n)
#pragma unroll
        for (int i = 0; i < 4; ++i) {
          int r = r0 + m * 16 + lg * 4 + i;
          int c = c0 + n * 16 + l15;
          out[(size_t)r * 1024 + c] = acc[m][n][i] + bvec[c];
        }
  } else {
    u16* dq = (u16*)dstbase + (size_t)z * 4096 * 1024;
#pragma unroll
    for (int m = 0; m < 4; ++m)
#pragma unroll
      for (int n = 0; n < 4; ++n)
#pragma unroll
        for (int i = 0; i < 4; ++i) {
          int r = r0 + m * 16 + lg * 4 + i;
          int c = c0 + n * 16 + l15;
          float v = acc[m][n][i];
          if (z == 0) v *= 0.125f;                                   // q / sqrt(64)
          else if (z == 3) v = 1.f / (1.f + __expf(-(v + bvec[c]))); // sigmoid gate
          dq[(size_t)r * 1024 + c] = f2bf(v);
        }
  }
}

// ---------------- flash attention v6: QBLK=128, 4 waves x 32q, window 32 ----------------
// R5 structure with the bias-row bugfix: COMPUTE reads bias rows at the wave's
// global q offset (w*32 + qa*16 + l15), matching the [128][32] staged tile.
__global__ __launch_bounds__(256, 2) void attn_kernel(
    const u16* __restrict__ qws, const u16* __restrict__ kws,
    const u16* __restrict__ vt, const u16* __restrict__ gws,
    const float* __restrict__ bias, const float* __restrict__ mask,
    u16* __restrict__ og) {
  const int tid = threadIdx.x;
  const int lane = tid & 63;
  const int w = tid >> 6;            // wave 0..3, owns q rows w*32..w*32+31
  const int l15 = lane & 15, lg = lane >> 4;
  const int bx = blockIdx.x;         // packs (qt 0..15, b); partners 8 apart -> same XCD
  const int qt = (bx & 7) | ((bx >> 4) << 3);
  const int b = (bx >> 3) & 1;
  const int h = blockIdx.y;

  __shared__ __align__(16) u16 ring[3][8192];   // [slot][ K 2048 | V 2048 | bias 4096 ]
  __shared__ __align__(16) u16 lsP[4][32 * 40]; // per-wave P, padded stride 40
  __shared__ __align__(16) u16 lsM[2048];       // additive mask bf16 (own batch)

  const float* bias_base = bias + ((size_t)h * 2048 + qt * 128) * 2048;
  const u16* vt_base = vt + (size_t)((b * 16 + h) * 64) * 2048;
  const u16* k_base = kws + (size_t)(b * 2048) * 1024 + h * 64;

  // ---- one-time: mask -> additive bf16 LDS
  {
    float4 m0 = *(const float4*)(mask + b * 2048 + tid * 8);
    float4 m1 = *(const float4*)(mask + b * 2048 + tid * 8 + 4);
    short8 mm;
    mm[0] = (short)f2bf((m0.x - 1.f) * 1e9f); mm[1] = (short)f2bf((m0.y - 1.f) * 1e9f);
    mm[2] = (short)f2bf((m0.z - 1.f) * 1e9f); mm[3] = (short)f2bf((m0.w - 1.f) * 1e9f);
    mm[4] = (short)f2bf((m1.x - 1.f) * 1e9f); mm[5] = (short)f2bf((m1.y - 1.f) * 1e9f);
    mm[6] = (short)f2bf((m1.z - 1.f) * 1e9f); mm[7] = (short)f2bf((m1.w - 1.f) * 1e9f);
    *(short8*)&lsM[tid * 8] = mm;
  }

  // ---- Q fragments (2 q-subtiles x 2 c-halves), force-materialize before DMA
  short8 qf[2][2];
#pragma unroll
  for (int qa = 0; qa < 2; ++qa)
#pragma unroll
    for (int ch = 0; ch < 2; ++ch)
      qf[qa][ch] = *(const short8*)(qws +
          (size_t)(b * 2048 + qt * 128 + w * 32 + qa * 16 + l15) * 1024 +
          h * 64 + ch * 32 + lg * 8);
  asm volatile("" :: "v"(qf[0][0]), "v"(qf[0][1]), "v"(qf[1][0]), "v"(qf[1][1]));

  asm volatile("s_waitcnt lgkmcnt(0)" ::: "memory");
  __builtin_amdgcn_sched_barrier(0);
  __builtin_amdgcn_s_barrier();     // lsM visible

  f32x4 O[2][4] = {};               // O[qa][cf] : c=cf*16+lg*4+i, q=qa*16+l15
  float mreg[2] = {-1e30f, -1e30f}, lreg[2] = {0.f, 0.f};
  f32x4 bA0, bA1, bA2, bA3, bB0, bB1, bB2, bB3;

#define STAGE_KV(SLOT, KW) {                                                         \
    int r_ = tid >> 3, cg_ = tid & 7;                                                \
    GLOAD_LDS16(k_base + (size_t)((KW) * 32 + r_) * 1024 + ((cg_ ^ (r_ & 7)) * 8),   \
                &ring[SLOT][tid * 8]);                                               \
    int c_ = tid >> 2, kg_ = tid & 3;                                                \
    GLOAD_LDS16(vt_base + (size_t)c_ * 2048 + (KW) * 32 + ((kg_ ^ (c_ & 3)) * 8),    \
                &ring[SLOT][2048 + tid * 8]); }

#define BIAS_ISSUE(R0, R1, R2, R3, KW) {                                             \
    const float* bp_ = bias_base + (size_t)(tid >> 3) * 2048 + (KW) * 32 + (tid & 7) * 4; \
    asm volatile("global_load_dwordx4 %0, %1, off" : "=v"(R0) : "v"(bp_));           \
    asm volatile("global_load_dwordx4 %0, %1, off" : "=v"(R1) : "v"(bp_ + 32 * 2048)); \
    asm volatile("global_load_dwordx4 %0, %1, off" : "=v"(R2) : "v"(bp_ + 64 * 2048)); \
    asm volatile("global_load_dwordx4 %0, %1, off" : "=v"(R3) : "v"(bp_ + 96 * 2048)); }

#define BW1(RV, LI, SLOT, MK) {                                                      \
    int q2_ = (tid >> 3) + (LI) * 32;                                                \
    short4v pk_;                                                                     \
    pk_[0] = (short)f2bf(RV[0] + bf2f((u16)MK[0]));                                  \
    pk_[1] = (short)f2bf(RV[1] + bf2f((u16)MK[1]));                                  \
    pk_[2] = (short)f2bf(RV[2] + bf2f((u16)MK[2]));                                  \
    pk_[3] = (short)f2bf(RV[3] + bf2f((u16)MK[3]));                                  \
    *(short4v*)&ring[SLOT][4096 + q2_ * 32 + (((tid & 7) ^ (q2_ & 7)) * 4)] = pk_; }

#define BIAS_WRITE(R0, R1, R2, R3, SLOT, KW) {                                       \
    short4v mk_ = *(const short4v*)&lsM[(KW) * 32 + (tid & 7) * 4];                  \
    BW1(R0, 0, SLOT, mk_); BW1(R1, 1, SLOT, mk_);                                    \
    BW1(R2, 2, SLOT, mk_); BW1(R3, 3, SLOT, mk_); }

#define COMPUTE(SLOT) {                                                              \
    __builtin_amdgcn_sched_barrier(0);                                               \
    const u16* Kc_ = &ring[SLOT][0];                                                 \
    const u16* Vc_ = &ring[SLOT][2048];                                              \
    const u16* Bc_ = &ring[SLOT][4096];                                              \
    short8 kf_[2][2];                                                                \
    _Pragma("unroll") for (int ks = 0; ks < 2; ++ks) {                               \
      int krow_ = ks * 16 + l15;                                                     \
      kf_[ks][0] = *(const short8*)&Kc_[krow_ * 64 + ((lg ^ (l15 & 7)) * 8)];        \
      kf_[ks][1] = *(const short8*)&Kc_[krow_ * 64 + (((4 + lg) ^ (l15 & 7)) * 8)];  \
    }                                                                                \
    f32x4 s_[2][2];                                                                  \
    _Pragma("unroll") for (int qa = 0; qa < 2; ++qa)                                 \
      _Pragma("unroll") for (int ks = 0; ks < 2; ++ks) {                             \
        f32x4 z_ = {0.f, 0.f, 0.f, 0.f};                                             \
        s_[qa][ks] = MFMA16(kf_[ks][0], qf[qa][0], z_, 0, 0, 0);                     \
        s_[qa][ks] = MFMA16(kf_[ks][1], qf[qa][1], s_[qa][ks], 0, 0, 0);             \
      }                                                                              \
    _Pragma("unroll") for (int qa = 0; qa < 2; ++qa) {                               \
      int q2_ = qa * 16 + l15;              /* wave-local q (P tile) */              \
      int qg_ = w * 32 + q2_;               /* global q in 128-tile (bias) */        \
      _Pragma("unroll") for (int ks = 0; ks < 2; ++ks) {                             \
        short4v bv_ = *(const short4v*)&Bc_[qg_ * 32 + (((ks * 4 + lg) ^ (qg_ & 7)) * 4)]; \
        _Pragma("unroll") for (int i = 0; i < 4; ++i)                                \
          s_[qa][ks][i] += bf2f((u16)bv_[i]);                                        \
      }                                                                              \
      float mt_ = fmaxf(fmaxf(fmaxf(s_[qa][0][0], s_[qa][0][1]),                     \
                              fmaxf(s_[qa][0][2], s_[qa][0][3])),                    \
                        fmaxf(fmaxf(s_[qa][1][0], s_[qa][1][1]),                     \
                              fmaxf(s_[qa][1][2], s_[qa][1][3])));                   \
      mt_ = fmaxf(mt_, __shfl_xor(mt_, 16));                                         \
      mt_ = fmaxf(mt_, __shfl_xor(mt_, 32));                                         \
      float nm_ = fmaxf(mreg[qa], mt_);                                              \
      float sc_ = __expf(mreg[qa] - nm_);                                            \
      mreg[qa] = nm_;                                                                \
      float rs_ = 0.f;                                                               \
      _Pragma("unroll") for (int ks = 0; ks < 2; ++ks)                               \
        _Pragma("unroll") for (int i = 0; i < 4; ++i) {                              \
          float p_ = __expf(s_[qa][ks][i] - nm_);                                    \
          s_[qa][ks][i] = p_; rs_ += p_;                                             \
        }                                                                            \
      rs_ += __shfl_xor(rs_, 16); rs_ += __shfl_xor(rs_, 32);                        \
      lreg[qa] = lreg[qa] * sc_ + rs_;                                               \
      _Pragma("unroll") for (int cf = 0; cf < 4; ++cf)                               \
        _Pragma("unroll") for (int i = 0; i < 4; ++i) O[qa][cf][i] *= sc_;           \
      _Pragma("unroll") for (int ks = 0; ks < 2; ++ks) {                             \
        short4v pk_;                                                                 \
        pk_[0] = (short)f2bf(s_[qa][ks][0]); pk_[1] = (short)f2bf(s_[qa][ks][1]);    \
        pk_[2] = (short)f2bf(s_[qa][ks][2]); pk_[3] = (short)f2bf(s_[qa][ks][3]);    \
        *(short4v*)&lsP[w][q2_ * 40 + ks * 16 + lg * 4] = pk_;                       \
      }                                                                              \
    }                                                                                \
    short8 vf_[4];                                                                   \
    _Pragma("unroll") for (int cf = 0; cf < 4; ++cf) {                               \
      int c_ = cf * 16 + l15;                                                        \
      vf_[cf] = *(const short8*)&Vc_[c_ * 32 + ((lg ^ (c_ & 3)) * 8)];               \
    }                                                                                \
    _Pragma("unroll") for (int qa = 0; qa < 2; ++qa) {                               \
      short8 pf_ = *(const short8*)&lsP[w][(qa * 16 + l15) * 40 + lg * 8];           \
      _Pragma("unroll") for (int cf = 0; cf < 4; ++cf)                               \
        O[qa][cf] = MFMA16(vf_[cf], pf_, O[qa][cf], 0, 0, 0);                        \
    } }

#define BODY(KB, L0, L1, L2, L3, W0, W1, W2, W3) {                                   \
    if ((KB) + 2 < 64) {                                                             \
      BIAS_ISSUE(L0, L1, L2, L3, (KB) + 2);                                          \
      STAGE_KV(((KB) + 2) % 3, (KB) + 2);                                            \
    }                                                                                \
    if ((KB) == 63) {                                                                \
      asm volatile("s_waitcnt vmcnt(0)" ::: "memory");                               \
      __builtin_amdgcn_sched_barrier(0);                                             \
      __builtin_amdgcn_s_barrier();                                                  \
    }                                                                                \
    COMPUTE((KB) % 3);                                                               \
    if ((KB) + 1 < 64) {                                                             \
      if ((KB) + 2 < 64) { asm volatile("s_waitcnt vmcnt(6)" ::: "memory"); }        \
      else { asm volatile("s_waitcnt vmcnt(2)" ::: "memory"); }                      \
      __builtin_amdgcn_sched_barrier(0);                                             \
      BIAS_WRITE(W0, W1, W2, W3, ((KB) + 1) % 3, (KB) + 1);                          \
    }                                                                                \
    asm volatile("s_waitcnt lgkmcnt(0)" ::: "memory");                               \
    __builtin_amdgcn_sched_barrier(0);                                               \
    __builtin_amdgcn_s_barrier(); }

  // ---- prologue: bias0->A, KV0, bias1->B, KV1; write bias0; drain KV0
  BIAS_ISSUE(bA0, bA1, bA2, bA3, 0);
  STAGE_KV(0, 0);
  BIAS_ISSUE(bB0, bB1, bB2, bB3, 1);
  STAGE_KV(1, 1);
  asm volatile("s_waitcnt vmcnt(8)" ::: "memory");
  __builtin_amdgcn_sched_barrier(0);
  BIAS_WRITE(bA0, bA1, bA2, bA3, 0, 0);
  asm volatile("s_waitcnt vmcnt(6)" ::: "memory");
  asm volatile("s_waitcnt lgkmcnt(0)" ::: "memory");
  __builtin_amdgcn_sched_barrier(0);
  __builtin_amdgcn_s_barrier();

  for (int kb2 = 0; kb2 < 64; kb2 += 2) {
    BODY(kb2,     bA0, bA1, bA2, bA3, bB0, bB1, bB2, bB3);  // even: issue A, write B
    BODY(kb2 + 1, bB0, bB1, bB2, bB3, bA0, bA1, bA2, bA3);  // odd:  issue B, write A
  }

  // ---- epilogue: normalize, bounce via LDS, gate, coalesced store
  float* ob = (float*)&ring[0][0];  // 4 waves x [32][65] f32
  {
    float inv0 = 1.f / lreg[0], inv1 = 1.f / lreg[1];
#pragma unroll
    for (int cf = 0; cf < 4; ++cf)
#pragma unroll
      for (int i = 0; i < 4; ++i) {
        ob[w * 2080 + (0 * 16 + l15) * 65 + cf * 16 + lg * 4 + i] = O[0][cf][i] * inv0;
        ob[w * 2080 + (1 * 16 + l15) * 65 + cf * 16 + lg * 4 + i] = O[1][cf][i] * inv1;
      }
  }
  __syncthreads();
  {
    int q2 = tid >> 1, c0 = (tid & 1) * 32;
    int w2 = q2 >> 5, r = q2 & 31;
    size_t rowoff = (size_t)(b * 2048 + qt * 128 + q2) * 1024 + h * 64 + c0;
#pragma unroll
    for (int ch = 0; ch < 4; ++ch) {
      short8 g8 = *(const short8*)(gws + rowoff + ch * 8);
      short8 o8;
#pragma unroll
      for (int j = 0; j < 8; ++j)
        o8[j] = (short)f2bf(ob[w2 * 2080 + r * 65 + c0 + ch * 8 + j] * bf2f((u16)g8[j]));
      *(short8*)(og + rowoff + ch * 8) = o8;
    }
  }
#undef STAGE_KV
#undef BIAS_ISSUE
#undef BW1
#undef BIAS_WRITE
#undef COMPUTE
#undef BODY
}

extern "C" void kernel_launch(void* const* d_in, const int* in_sizes, int n_in,
                              void* d_out, int out_size, void* d_ws, size_t ws_size,
                              hipStream_t stream) {
  const float* x    = (const float*)d_in[0];
  const float* mask = (const float*)d_in[1];
  const float* bias = (const float*)d_in[2];
  const float* wq   = (const float*)d_in[3];
  const float* wk   = (const float*)d_in[4];
  const float* wv   = (const float*)d_in[5];
  const float* wg   = (const float*)d_in[6];
  const float* bg   = (const float*)d_in[7];
  const float* wo   = (const float*)d_in[8];
  const float* bo   = (const float*)d_in[9];
  float* out = (float*)d_out;

  char* ws = (char*)d_ws;
  const size_t MB = 1ull << 20;
  u16* xb   = (u16*)(ws + 0);        // 4096x1024 bf16 input          (8 MB)
  u16* wt   = (u16*)(ws + 8 * MB);   // 4x WT [1024][1024] bf16       (8 MB)
  u16* wot  = (u16*)(ws + 16 * MB);  // WOT [1024][1024] bf16         (2 MB)
  u16* proj = (u16*)(ws + 18 * MB);  // q,k,v,g each 4096x1024 bf16   (32 MB)
  u16* vtp  = (u16*)(ws + 50 * MB);  // VT [b,h,c,s] bf16             (8 MB)
  u16* og   = (u16*)(ws + 58 * MB);  // gated attention out bf16      (8 MB)
  const size_t PSZ = (size_t)4096 * 1024;

  convert_bf16_kernel<<<2048, 256, 0, stream>>>(x, xb, 4096 * 1024);

  dim3 tg(16, 16);
  transpose_w64<<<tg, 256, 0, stream>>>(wq, wt + 0 * 1048576, 1024, 1024);
  transpose_w64<<<tg, 256, 0, stream>>>(wk, wt + 1 * 1048576, 1024, 1024);
  transpose_w64<<<tg, 256, 0, stream>>>(wv, wt + 2 * 1048576, 1024, 1024);
  transpose_w64<<<tg, 256, 0, stream>>>(wg, wt + 3 * 1048576, 1024, 1024);
  transpose_w64<<<tg, 256, 0, stream>>>(wo, wot, 1024, 1024);

  gemm_bt128<<<dim3(32, 8, 4), 256, 0, stream>>>(xb, wt, (void*)proj, bg, -1);

  transpose_v64<<<dim3(32, 32), 256, 0, stream>>>(proj + 2 * PSZ, vtp);

  attn_kernel<<<dim3(32, 16), 256, 0, stream>>>(proj, proj + PSZ, vtp, proj + 3 * PSZ,
                                                bias, mask, og);

  gemm_bt128<<<dim3(32, 8, 1), 256, 0, stream>>>(og, wot, (void*)out, bo, 4);
}

// Round 7
// 222.549 us; speedup vs baseline: 1.1766x; 1.1766x over previous
//
#include <hip/hip_runtime.h>
#include <hip/hip_bf16.h>
#include <stdint.h>

typedef unsigned short u16;
typedef __attribute__((ext_vector_type(8))) short short8;
typedef __attribute__((ext_vector_type(4))) short short4v;
typedef __attribute__((ext_vector_type(4))) float f32x4;

#define MFMA16 __builtin_amdgcn_mfma_f32_16x16x32_bf16

#define GLOAD_LDS16(gsrc, ldst) \
  __builtin_amdgcn_global_load_lds((const __attribute__((address_space(1))) void*)(gsrc), \
                                   (__attribute__((address_space(3))) void*)(ldst), 16, 0, 0)

__device__ __forceinline__ u16 f2bf(float x) {
  union { float f; uint32_t u; } v; v.f = x;
  uint32_t r = v.u + 0x7FFFu + ((v.u >> 16) & 1u);
  return (u16)(r >> 16);
}
__device__ __forceinline__ u16 f2bf_rn(float x) {
  __hip_bfloat16 h = __float2bfloat16(x);
  return *reinterpret_cast<u16*>(&h);
}
__device__ __forceinline__ float bf2f(u16 b) {
  union { uint32_t u; float f; } v; v.u = ((uint32_t)b) << 16;
  return v.f;
}

// ---------------- convert f32 -> bf16 (elementwise, vectorized) ----------------
__global__ __launch_bounds__(256) void convert_bf16_kernel(
    const float* __restrict__ in, u16* __restrict__ out, int n) {
  int i = (blockIdx.x * 256 + threadIdx.x) * 8;
  if (i >= n) return;
  float4 a = *(const float4*)(in + i);
  float4 b = *(const float4*)(in + i + 4);
  short8 t;
  t[0] = (short)f2bf(a.x); t[1] = (short)f2bf(a.y);
  t[2] = (short)f2bf(a.z); t[3] = (short)f2bf(a.w);
  t[4] = (short)f2bf(b.x); t[5] = (short)f2bf(b.y);
  t[6] = (short)f2bf(b.z); t[7] = (short)f2bf(b.w);
  *(short8*)(out + i) = t;
}

// ---------------- transpose f32 [K][N] -> bf16 [N][K] (64x64 tiles) ----------------
__global__ __launch_bounds__(256) void transpose_w64(
    const float* __restrict__ W, u16* __restrict__ WT, int KK, int NN) {
  __shared__ float tile[64][68];
  const int t = threadIdx.x;
  const int k0 = blockIdx.x * 64, n0 = blockIdx.y * 64;
  {
    int r = t >> 2, c0 = (t & 3) * 16;
    const float* src = W + (size_t)(k0 + r) * NN + n0 + c0;
#pragma unroll
    for (int j = 0; j < 16; j += 4) {
      float4 v = *(const float4*)(src + j);
      tile[r][c0 + j + 0] = v.x; tile[r][c0 + j + 1] = v.y;
      tile[r][c0 + j + 2] = v.z; tile[r][c0 + j + 3] = v.w;
    }
  }
  __syncthreads();
  {
    int n = t >> 2, kq = (t & 3) * 16;
    short8 t0, t1;
#pragma unroll
    for (int j = 0; j < 8; ++j)  t0[j] = (short)f2bf(tile[kq + j][n]);
#pragma unroll
    for (int j = 0; j < 8; ++j)  t1[j] = (short)f2bf(tile[kq + 8 + j][n]);
    u16* dst = WT + (size_t)(n0 + n) * KK + k0 + kq;
    *(short8*)dst = t0;
    *(short8*)(dst + 8) = t1;
  }
}

// ---------------- transpose V bf16 [b*2048+s][h*64+c] -> VT [(b*16+h)*64+c][s] ----------------
__global__ __launch_bounds__(256) void transpose_v64(
    const u16* __restrict__ vin, u16* __restrict__ vout) {
  __shared__ u16 tile[64][80];
  const int t = threadIdx.x;
  const int s0 = blockIdx.x * 64;
  const int bh = blockIdx.y;  // b*16+h
  const int b = bh >> 4, h = bh & 15;
  {
    int r = t >> 2, c0 = (t & 3) * 16;
    const u16* src = vin + (size_t)(b * 2048 + s0 + r) * 1024 + h * 64 + c0;
    *(short8*)&tile[r][c0] = *(const short8*)src;
    *(short8*)&tile[r][c0 + 8] = *(const short8*)(src + 8);
  }
  __syncthreads();
  {
    int c = t >> 2, s4 = (t & 3) * 16;
    short8 t0, t1;
#pragma unroll
    for (int j = 0; j < 8; ++j) t0[j] = (short)tile[s4 + j][c];
#pragma unroll
    for (int j = 0; j < 8; ++j) t1[j] = (short)tile[s4 + 8 + j][c];
    u16* dst = vout + (size_t)(bh * 64 + c) * 2048 + s0 + s4;
    *(short8*)dst = t0;
    *(short8*)(dst + 8) = t1;
  }
}

// ---------------- GEMM: D[r][n] = sum_k A[r][k]*BT[n][k], m97-style 128x128/BK=64 ----------------
__global__ __launch_bounds__(256) void gemm_bt128(
    const u16* __restrict__ A, const u16* __restrict__ BTbase,
    void* __restrict__ dstbase, const float* __restrict__ bvec, int mode) {
  const int K = 1024;
  const int tid = threadIdx.x, lane = tid & 63, w = tid >> 6;
  const int wr = w >> 1, wc = w & 1;
  const int l15 = lane & 15, lg = lane >> 4;
  const int z = (mode < 0) ? (int)blockIdx.z : mode;
  const u16* BT = (mode < 0) ? BTbase + (size_t)z * 1024 * 1024 : BTbase;
  const int rbase = blockIdx.x * 128;
  const int nbase = blockIdx.y * 128;
  __shared__ u16 lsA[128 * 64];
  __shared__ u16 lsB[128 * 64];
  f32x4 acc[4][4] = {};
  const int col8 = (lane & 7) * 8;
  for (int kt = 0; kt < K / 64; ++kt) {
#pragma unroll
    for (int i = 0; i < 4; ++i) {
      int row = w * 32 + i * 8 + (lane >> 3);
      const u16* sa = A + (size_t)(rbase + row) * K + kt * 64 + col8;
      GLOAD_LDS16(sa, lsA + (w * 32 + i * 8) * 64 + lane * 8);
      const u16* sb = BT + (size_t)(nbase + row) * K + kt * 64 + col8;
      GLOAD_LDS16(sb, lsB + (w * 32 + i * 8) * 64 + lane * 8);
    }
    __syncthreads();
#pragma unroll
    for (int kk = 0; kk < 2; ++kk) {
      short8 af[4], bfr[4];
#pragma unroll
      for (int m = 0; m < 4; ++m)
        af[m] = *(const short8*)&lsA[(wr * 64 + m * 16 + l15) * 64 + kk * 32 + lg * 8];
#pragma unroll
      for (int n = 0; n < 4; ++n)
        bfr[n] = *(const short8*)&lsB[(wc * 64 + n * 16 + l15) * 64 + kk * 32 + lg * 8];
#pragma unroll
      for (int m = 0; m < 4; ++m)
#pragma unroll
        for (int n = 0; n < 4; ++n)
          acc[m][n] = MFMA16(af[m], bfr[n], acc[m][n], 0, 0, 0);
    }
    __syncthreads();
  }
  const int r0 = rbase + wr * 64;
  const int c0 = nbase + wc * 64;
  if (z == 4) {
    float* out = (float*)dstbase;
#pragma unroll
    for (int m = 0; m < 4; ++m)
#pragma unroll
      for (int n = 0; n < 4; ++n)
#pragma unroll
        for (int i = 0; i < 4; ++i) {
          int r = r0 + m * 16 + lg * 4 + i;
          int c = c0 + n * 16 + l15;
          out[(size_t)r * 1024 + c] = acc[m][n][i] + bvec[c];
        }
  } else {
    u16* dq = (u16*)dstbase + (size_t)z * 4096 * 1024;
#pragma unroll
    for (int m = 0; m < 4; ++m)
#pragma unroll
      for (int n = 0; n < 4; ++n)
#pragma unroll
        for (int i = 0; i < 4; ++i) {
          int r = r0 + m * 16 + lg * 4 + i;
          int c = c0 + n * 16 + l15;
          float v = acc[m][n][i];
          if (z == 0) v *= 0.125f;                                   // q / sqrt(64)
          else if (z == 3) v = 1.f / (1.f + __expf(-(v + bvec[c]))); // sigmoid gate
          dq[(size_t)r * 1024 + c] = f2bf(v);
        }
  }
}

// ---------------- flash attention v7: 8 waves x 16q, bias direct-to-accumulator ----------------
// QBLK=128, window 32 k, 64 iters. LDS = 3-slot K/V ring (24KB) + P (10KB) + mask (4KB).
// Bias loads land in MFMA C-layout: C-init = bias + mask, QK^T accumulates on top.
// Exactly 3 VMEM/wave/iter (2 bias dwordx4 + 1 global_load_lds) -> counted vmcnt(3).
__global__ __launch_bounds__(512, 4) void attn_kernel(
    const u16* __restrict__ qws, const u16* __restrict__ kws,
    const u16* __restrict__ vt, const u16* __restrict__ gws,
    const float* __restrict__ bias, const float* __restrict__ mask,
    u16* __restrict__ og) {
  const int tid = threadIdx.x;
  const int lane = tid & 63;
  const int w = tid >> 6;            // wave 0..7, owns q rows qt*128 + w*16 .. +15
  const int l15 = lane & 15, lg = lane >> 4;
  const int bx = blockIdx.x;         // packs (qt 0..15, b); partners 8 apart -> same XCD
  const int qt = (bx & 7) | ((bx >> 4) << 3);
  const int b = (bx >> 3) & 1;
  const int h = blockIdx.y;

  __shared__ __align__(16) u16 ring[3][4096];   // [slot][ K 2048 u16 | V 2048 u16 ] swz
  __shared__ __align__(16) u16 lsP[8][640];     // per-wave P [16 q][stride 40]
  __shared__ __align__(16) u16 lsM[2048];       // additive mask bf16 (own batch)

  const float* bias_base = bias + ((size_t)h * 2048 + qt * 128) * 2048;
  const u16* vt_base = vt + (size_t)((b * 16 + h) * 64) * 2048;
  const u16* k_base = kws + (size_t)(b * 2048) * 1024 + h * 64;

  // ---- one-time: mask -> additive bf16 LDS (512 thr x 4)
  {
    float4 mv = *(const float4*)(mask + b * 2048 + tid * 4);
    short4v mm;
    mm[0] = (short)f2bf((mv.x - 1.f) * 1e9f); mm[1] = (short)f2bf((mv.y - 1.f) * 1e9f);
    mm[2] = (short)f2bf((mv.z - 1.f) * 1e9f); mm[3] = (short)f2bf((mv.w - 1.f) * 1e9f);
    *(short4v*)&lsM[tid * 4] = mm;
  }

  // ---- Q fragments (one 16-q subtile x 2 c-halves) + gate preload; force-materialize
  const size_t qrow = (size_t)(b * 2048 + qt * 128 + w * 16 + l15) * 1024 + h * 64;
  short8 qf0 = *(const short8*)(qws + qrow + 0 * 32 + lg * 8);
  short8 qf1 = *(const short8*)(qws + qrow + 1 * 32 + lg * 8);
  short4v g4[4];
#pragma unroll
  for (int cf = 0; cf < 4; ++cf)
    g4[cf] = *(const short4v*)(gws + qrow + cf * 16 + lg * 4);
  asm volatile("" :: "v"(qf0), "v"(qf1), "v"(g4[0]), "v"(g4[1]), "v"(g4[2]), "v"(g4[3]));
  asm volatile("s_waitcnt vmcnt(0)" ::: "memory");   // plain VMEM drained before counting

  f32x4 O[4] = {};                  // O[cf] : c=cf*16+lg*4+i, q=l15
  float mreg = -1e30f, lreg = 0.f;
  f32x4 bA0, bA1, bB0, bB1;

#define STAGE_KV(SLOT, KW) {                                                        \
    if (w < 4) {                                                                    \
      int g_ = tid;                                                                 \
      int r_ = g_ >> 3, cg_ = g_ & 7;                                               \
      GLOAD_LDS16(k_base + (size_t)((KW) * 32 + r_) * 1024 + ((cg_ ^ (r_ & 7)) * 8),\
                  &ring[SLOT][g_ * 8]);                                             \
    } else {                                                                        \
      int g_ = tid - 256;                                                           \
      int c_ = g_ >> 2, kg_ = g_ & 3;                                               \
      int sw_ = (c_ & 3) ^ ((c_ >> 2) & 3);                                         \
      GLOAD_LDS16(vt_base + (size_t)c_ * 2048 + (KW) * 32 + ((kg_ ^ sw_) * 8),      \
                  &ring[SLOT][2048 + g_ * 8]);                                      \
    } }

#define BIAS_ISSUE(R0, R1, KW) {                                                    \
    const float* bp_ = bias_base + (size_t)(w * 16 + l15) * 2048 + (KW) * 32 + lg * 4; \
    asm volatile("global_load_dwordx4 %0, %1, off" : "=v"(R0) : "v"(bp_));          \
    asm volatile("global_load_dwordx4 %0, %1, off" : "=v"(R1) : "v"(bp_ + 16));     \
  }

#define COMPUTE(SLOT, KB, BR0, BR1) {                                               \
    const u16* Kc_ = &ring[SLOT][0];                                                \
    const u16* Vc_ = &ring[SLOT][2048];                                             \
    const int sw_ = l15 & 7;                                                        \
    short8 kf0a = *(const short8*)&Kc_[(l15) * 64 + ((lg ^ sw_) * 8)];              \
    short8 kf0b = *(const short8*)&Kc_[(l15) * 64 + (((4 + lg) ^ sw_) * 8)];        \
    short8 kf1a = *(const short8*)&Kc_[(16 + l15) * 64 + ((lg ^ sw_) * 8)];         \
    short8 kf1b = *(const short8*)&Kc_[(16 + l15) * 64 + (((4 + lg) ^ sw_) * 8)];   \
    short4v mk0 = *(const short4v*)&lsM[(KB) * 32 + lg * 4];                        \
    short4v mk1 = *(const short4v*)&lsM[(KB) * 32 + 16 + lg * 4];                   \
    f32x4 ci0, ci1;                                                                 \
    _Pragma("unroll") for (int i = 0; i < 4; ++i) {                                 \
      ci0[i] = BR0[i] + bf2f((u16)mk0[i]);                                          \
      ci1[i] = BR1[i] + bf2f((u16)mk1[i]);                                          \
    }                                                                               \
    f32x4 s0 = MFMA16(kf0a, qf0, ci0, 0, 0, 0);                                     \
    s0 = MFMA16(kf0b, qf1, s0, 0, 0, 0);                                            \
    f32x4 s1 = MFMA16(kf1a, qf0, ci1, 0, 0, 0);                                     \
    s1 = MFMA16(kf1b, qf1, s1, 0, 0, 0);                                            \
    float mt_ = fmaxf(fmaxf(fmaxf(s0[0], s0[1]), fmaxf(s0[2], s0[3])),              \
                      fmaxf(fmaxf(s1[0], s1[1]), fmaxf(s1[2], s1[3])));             \
    mt_ = fmaxf(mt_, __shfl_xor(mt_, 16));                                          \
    mt_ = fmaxf(mt_, __shfl_xor(mt_, 32));                                          \
    float nm_ = fmaxf(mreg, mt_);                                                   \
    float sc_ = __expf(mreg - nm_);                                                 \
    mreg = nm_;                                                                     \
    float rs_ = 0.f;                                                                \
    _Pragma("unroll") for (int i = 0; i < 4; ++i) {                                 \
      s0[i] = __expf(s0[i] - nm_); rs_ += s0[i];                                    \
      s1[i] = __expf(s1[i] - nm_); rs_ += s1[i];                                    \
    }                                                                               \
    rs_ += __shfl_xor(rs_, 16);                                                     \
    rs_ += __shfl_xor(rs_, 32);                                                     \
    lreg = lreg * sc_ + rs_;                                                        \
    _Pragma("unroll") for (int cf = 0; cf < 4; ++cf)                                \
      _Pragma("unroll") for (int i = 0; i < 4; ++i) O[cf][i] *= sc_;                \
    short4v p0_, p1_;                                                               \
    _Pragma("unroll") for (int i = 0; i < 4; ++i) {                                 \
      p0_[i] = (short)f2bf_rn(s0[i]);                                               \
      p1_[i] = (short)f2bf_rn(s1[i]);                                               \
    }                                                                               \
    *(short4v*)&lsP[w][l15 * 40 + lg * 4] = p0_;                                    \
    *(short4v*)&lsP[w][l15 * 40 + 16 + lg * 4] = p1_;                               \
    short8 pf_ = *(const short8*)&lsP[w][l15 * 40 + lg * 8];                        \
    _Pragma("unroll") for (int cf = 0; cf < 4; ++cf) {                              \
      int c_ = cf * 16 + l15;                                                       \
      short8 vf_ = *(const short8*)&Vc_[c_ * 32 +                                   \
                                        ((lg ^ ((c_ & 3) ^ ((c_ >> 2) & 3))) * 8)]; \
      O[cf] = MFMA16(vf_, pf_, O[cf], 0, 0, 0);                                     \
    } }

#define BODY(KB, BR0, BR1) {                                                        \
    if ((KB) + 2 < 64) STAGE_KV(((KB) + 2) % 3, (KB) + 2);                          \
    COMPUTE((KB) % 3, KB, BR0, BR1);                                                \
    if ((KB) + 2 < 64) {                                                            \
      BIAS_ISSUE(BR0, BR1, (KB) + 2);                                               \
      asm volatile("s_waitcnt vmcnt(3)" ::: "memory");                              \
    } else {                                                                        \
      asm volatile("s_waitcnt vmcnt(0)" ::: "memory");                              \
    }                                                                               \
    asm volatile("s_waitcnt lgkmcnt(0)" ::: "memory");                              \
    __builtin_amdgcn_sched_barrier(0);                                              \
    __builtin_amdgcn_s_barrier(); }

  // ---- prologue: bias(0)->A, KV(0), bias(1)->B, KV(1); drain set 0; publish lsM
  BIAS_ISSUE(bA0, bA1, 0);
  STAGE_KV(0, 0);
  BIAS_ISSUE(bB0, bB1, 1);
  STAGE_KV(1, 1);
  asm volatile("s_waitcnt vmcnt(3)" ::: "memory");
  asm volatile("s_waitcnt lgkmcnt(0)" ::: "memory");
  __builtin_amdgcn_sched_barrier(0);
  __builtin_amdgcn_s_barrier();

  for (int kb2 = 0; kb2 < 64; kb2 += 2) {
    BODY(kb2,     bA0, bA1);   // even: consumes+reissues set A
    BODY(kb2 + 1, bB0, bB1);   // odd:  consumes+reissues set B
  }

  // ---- epilogue: normalize, gate (preloaded), store bf16 (4x short4v per lane)
  {
    float inv = 1.f / lreg;
#pragma unroll
    for (int cf = 0; cf < 4; ++cf) {
      short4v o4;
#pragma unroll
      for (int i = 0; i < 4; ++i)
        o4[i] = (short)f2bf_rn(O[cf][i] * inv * bf2f((u16)g4[cf][i]));
      *(short4v*)(og + qrow + cf * 16 + lg * 4) = o4;
    }
  }
#undef STAGE_KV
#undef BIAS_ISSUE
#undef COMPUTE
#undef BODY
}

extern "C" void kernel_launch(void* const* d_in, const int* in_sizes, int n_in,
                              void* d_out, int out_size, void* d_ws, size_t ws_size,
                              hipStream_t stream) {
  const float* x    = (const float*)d_in[0];
  const float* mask = (const float*)d_in[1];
  const float* bias = (const float*)d_in[2];
  const float* wq   = (const float*)d_in[3];
  const float* wk   = (const float*)d_in[4];
  const float* wv   = (const float*)d_in[5];
  const float* wg   = (const float*)d_in[6];
  const float* bg   = (const float*)d_in[7];
  const float* wo   = (const float*)d_in[8];
  const float* bo   = (const float*)d_in[9];
  float* out = (float*)d_out;

  char* ws = (char*)d_ws;
  const size_t MB = 1ull << 20;
  u16* xb   = (u16*)(ws + 0);        // 4096x1024 bf16 input          (8 MB)
  u16* wt   = (u16*)(ws + 8 * MB);   // 4x WT [1024][1024] bf16       (8 MB)
  u16* wot  = (u16*)(ws + 16 * MB);  // WOT [1024][1024] bf16         (2 MB)
  u16* proj = (u16*)(ws + 18 * MB);  // q,k,v,g each 4096x1024 bf16   (32 MB)
  u16* vtp  = (u16*)(ws + 50 * MB);  // VT [b,h,c,s] bf16             (8 MB)
  u16* og   = (u16*)(ws + 58 * MB);  // gated attention out bf16      (8 MB)
  const size_t PSZ = (size_t)4096 * 1024;

  convert_bf16_kernel<<<2048, 256, 0, stream>>>(x, xb, 4096 * 1024);

  dim3 tg(16, 16);
  transpose_w64<<<tg, 256, 0, stream>>>(wq, wt + 0 * 1048576, 1024, 1024);
  transpose_w64<<<tg, 256, 0, stream>>>(wk, wt + 1 * 1048576, 1024, 1024);
  transpose_w64<<<tg, 256, 0, stream>>>(wv, wt + 2 * 1048576, 1024, 1024);
  transpose_w64<<<tg, 256, 0, stream>>>(wg, wt + 3 * 1048576, 1024, 1024);
  transpose_w64<<<tg, 256, 0, stream>>>(wo, wot, 1024, 1024);

  gemm_bt128<<<dim3(32, 8, 4), 256, 0, stream>>>(xb, wt, (void*)proj, bg, -1);

  transpose_v64<<<dim3(32, 32), 256, 0, stream>>>(proj + 2 * PSZ, vtp);

  attn_kernel<<<dim3(32, 16), 512, 0, stream>>>(proj, proj + PSZ, vtp, proj + 3 * PSZ,
                                                bias, mask, og);

  gemm_bt128<<<dim3(32, 8, 1), 256, 0, stream>>>(og, wot, (void*)out, bo, 4);
}